// Round 25
// baseline (172.379 us; speedup 1.0000x reference)
//
#include <hip/hip_runtime.h>
#include <math.h>

#define N_NODES 20000
#define N_EDGES 200000
#define DM 128
#define NH 8

typedef __attribute__((ext_vector_type(8))) short bf16x8;
typedef __attribute__((ext_vector_type(4))) float f32x4;

__device__ __forceinline__ unsigned short f2b(float f) {
  unsigned int u = __float_as_uint(f);
  unsigned int r = (u + 0x7FFFu + ((u >> 16) & 1u)) >> 16;  // RNE
  return (unsigned short)r;
}
__device__ __forceinline__ float b2f(unsigned short s) {
  return __uint_as_float(((unsigned int)s) << 16);
}

// ---------------- deg zero ----------------
__global__ __launch_bounds__(256) void degzero(int* __restrict__ deg) {
  int i = blockIdx.x * 256 + threadIdx.x;
  if (i < N_NODES) deg[i] = 0;
}

// ---------------- prep: cast + edge count(rank) + all weight prep ----------------
__global__ __launch_bounds__(256) void prep_all(
    const float* __restrict__ x, float* __restrict__ h, unsigned short* __restrict__ hb,
    const int* __restrict__ dstE, int* __restrict__ deg, int* __restrict__ rank,
    const float* __restrict__ Ws, unsigned short* __restrict__ wsz,
    const float* __restrict__ W_last, unsigned short* __restrict__ wpsz,
    const float* __restrict__ al_last, const float* __restrict__ ar_last,
    const float* __restrict__ b_last, unsigned short* __restrict__ wlrsz,
    float* __restrict__ mb) {
  int i = blockIdx.x * 256 + threadIdx.x;
  if (i < (N_NODES * DM) / 4) {  // float4 cast
    float4 v = ((const float4*)x)[i];
    ((float4*)h)[i] = v;
    ((ushort4*)hb)[i] = make_ushort4(f2b(v.x), f2b(v.y), f2b(v.z), f2b(v.w));
  }
  if (i < N_EDGES) rank[i] = atomicAdd(&deg[dstE[i]], 1);
  if (i < 2 * 16384) {  // layers 0/1 B swizzle
    int layer = i >> 14;
    int r = i & 16383;
    int j = r & 7, l = (r >> 3) & 63, f = (r >> 9) & 7, ks = r >> 12;
    int k = ks * 32 + ((l >> 4) << 3) + j;
    int n = f * 16 + (l & 15);
    wsz[i] = f2b(Ws[(size_t)layer * 16384 + k * 128 + n]);
  }
  if (i < 131072) {  // last-layer B swizzle (1/8 mean folded)
    int j = i & 7, l = (i >> 3) & 63, f = (i >> 9) & 7, ks = i >> 12;
    int k = ks * 32 + ((l >> 4) << 3) + j;
    int n = f * 16 + (l & 15);
    int h_ = k >> 7, ko = k & 127;
    wpsz[i] = f2b(W_last[(size_t)ko * 1024 + h_ * 128 + n] * 0.125f);
  }
  if (i < 2048) {  // wlr fragment build
    int j = i & 7, l = (i >> 3) & 63, ks = i >> 9;
    int k = ks * 32 + ((l >> 4) << 3) + j;
    int n = l & 15;
    int hh = n & 7;
    const float* av = (n < 8) ? (al_last + hh * 128) : (ar_last + hh * 128);
    float s = 0.f;
    for (int d = 0; d < 128; ++d) s += W_last[(size_t)k * 1024 + hh * 128 + d] * av[d];
    wlrsz[i] = f2b(s);
  }
  if (i < 128) {
    float s = 0.f;
#pragma unroll
    for (int hh = 0; hh < 8; ++hh) s += b_last[hh * 128 + i];
    mb[i] = s * 0.125f;
  }
}

// ---------------- single-block (1024 thr): exclusive scan (off) + bucket bases ----------------
__global__ void scan_deg(const int* __restrict__ deg, int* __restrict__ off,
                         int* __restrict__ bbase_g, int* __restrict__ bcur_g) {
  __shared__ int part[1024];
  __shared__ int hist[16][64];
  const int tid = threadIdx.x;
  const int wv = tid >> 6, lane = tid & 63;
  const int CHUNK = (N_NODES + 1023) / 1024;  // 20
  int base = tid * CHUNK;

  for (int i = tid; i < 16 * 64; i += 1024) ((int*)hist)[i] = 0;
  __syncthreads();

  int s = 0;
  for (int i = 0; i < CHUNK; ++i) {
    int idx = base + i;
    if (idx < N_NODES) {
      int d = deg[idx];
      s += d;
      atomicAdd(&hist[wv][min(d, 63)], 1);
    }
  }
  part[tid] = s;
  __syncthreads();
  for (int ofs = 1; ofs < 1024; ofs <<= 1) {
    int v = (tid >= ofs) ? part[tid - ofs] : 0;
    __syncthreads();
    part[tid] += v;
    __syncthreads();
  }
  int run = (tid > 0) ? part[tid - 1] : 0;
  for (int i = 0; i < CHUNK; ++i) {
    int idx = base + i;
    if (idx < N_NODES) {
      off[idx] = run;
      run += deg[idx];
    }
  }
  if (tid == 0) off[N_NODES] = part[1023];

  // bucket bases: wave 0 reduces the 16 sub-histograms + shfl exclusive scan
  if (wv == 0) {
    int c = 0;
#pragma unroll
    for (int w = 0; w < 16; ++w) c += hist[w][lane];
    int inc = c;
#pragma unroll
    for (int ofs = 1; ofs < 64; ofs <<= 1) {
      int v = __shfl_up(inc, ofs, 64);
      if (lane >= ofs) inc += v;
    }
    bbase_g[lane] = inc - c;  // exclusive
    bcur_g[lane] = 0;
  }
}

// ---------------- MFMA GEMM device body (layer 0) ----------------
template <int K>
__device__ __forceinline__ void dev_gemm(int tile, const unsigned short* __restrict__ A,
                                         const unsigned short* __restrict__ Bsz,
                                         unsigned short* __restrict__ Cb,
                                         const float* __restrict__ al,
                                         const float* __restrict__ ar,
                                         float* __restrict__ elr, int lane, int wid) {
  const int wrow = wid & 1, wc = wid >> 1;
  const int r0 = tile * 32;
  const int arow = r0 + wrow * 16 + (lane & 15);
  const int kg = lane >> 4;

  f32x4 acc[4];
#pragma unroll
  for (int fi = 0; fi < 4; ++fi) acc[fi] = {0.f, 0.f, 0.f, 0.f};

  const bf16x8* Ap = (const bf16x8*)(A + (size_t)arow * K + kg * 8);
#pragma unroll 4
  for (int ks = 0; ks < K / 32; ++ks) {
    bf16x8 a = Ap[ks * 4];
#pragma unroll
    for (int fi = 0; fi < 4; ++fi) {
      int f = wc * 4 + fi;
      bf16x8 b = *(const bf16x8*)(Bsz + (((size_t)(ks * 8 + f) * 64 + lane) << 3));
      acc[fi] = __builtin_amdgcn_mfma_f32_16x16x32_bf16(a, b, acc[fi], 0, 0, 0);
    }
  }

  const int rbase = r0 + wrow * 16 + (lane >> 4) * 4;
#pragma unroll
  for (int fi = 0; fi < 4; ++fi) {
    int col = wc * 64 + fi * 16 + (lane & 15);
#pragma unroll
    for (int r = 0; r < 4; ++r) {
      Cb[(size_t)(rbase + r) * DM + col] = f2b(acc[fi][r]);
    }
  }

  // fused attn scores
#pragma unroll
  for (int fi = 0; fi < 4; ++fi) {
    int hh = wc * 4 + fi;
    float alv = al[hh * 16 + (lane & 15)];
    float arv = ar[hh * 16 + (lane & 15)];
#pragma unroll
    for (int r = 0; r < 4; ++r) {
      float pl = acc[fi][r] * alv;
      float pr = acc[fi][r] * arv;
#pragma unroll
      for (int msk = 1; msk < 16; msk <<= 1) {
        pl += __shfl_xor(pl, msk, 64);
        pr += __shfl_xor(pr, msk, 64);
      }
      if ((lane & 15) == 0) {
        int row = rbase + r;
        elr[row * 16 + hh] = pl;
        elr[row * 16 + 8 + hh] = pr;
      }
    }
  }
}

// layer0 GEMM || rank-based CSR scatter || perm scatter (block-aggregated atomics)
__global__ __launch_bounds__(256) void gemm0_scatter(
    const unsigned short* __restrict__ A, const unsigned short* __restrict__ Bsz,
    unsigned short* __restrict__ Cb, const float* __restrict__ al,
    const float* __restrict__ ar, float* __restrict__ elr, const int* __restrict__ srcE,
    const int* __restrict__ dstE, const int* __restrict__ rank,
    const int* __restrict__ off, int* __restrict__ csr_src, const int* __restrict__ deg,
    const int* __restrict__ bbase_g, int* __restrict__ bcur_g, int* __restrict__ perm) {
  __shared__ int lcnt[64];
  __shared__ int gbase[64];
  const int bid = blockIdx.x;
  const int GB = N_NODES / 32;
  const int EB = (N_EDGES + 255) / 256;
  if (bid < GB) {
    dev_gemm<DM>(bid, A, Bsz, Cb, al, ar, elr, threadIdx.x & 63, threadIdx.x >> 6);
  } else if (bid < GB + EB) {
    int e = (bid - GB) * 256 + threadIdx.x;
    if (e < N_EDGES) {
      csr_src[off[dstE[e]] + rank[e]] = srcE[e];
    }
  } else {
    // perm scatter: LDS-local ranks + ONE global atomic per (block, nonzero bucket)
    const int tid = threadIdx.x;
    int idx = (bid - GB - EB) * 256 + tid;
    if (tid < 64) lcnt[tid] = 0;
    __syncthreads();
    int d = 0, lrank = 0;
    bool valid = idx < N_NODES;
    if (valid) {
      d = min(deg[idx], 63);
      lrank = atomicAdd(&lcnt[d], 1);  // <=4-way LDS contention, cheap
    }
    __syncthreads();
    if (tid < 64 && lcnt[tid] > 0) gbase[tid] = atomicAdd(&bcur_g[tid], lcnt[tid]);
    __syncthreads();
    if (valid) perm[bbase_g[d] + gbase[d] + lrank] = idx;
  }
}

// ---------------- layers 0/1: fused softmax+agg (perm-balanced, 2-deep gather pipeline) ----
template <int MODE>
__global__ __launch_bounds__(256) void fused_small(
    const int* __restrict__ perm, const int* __restrict__ off,
    const int* __restrict__ csr_src, const unsigned short* __restrict__ feat,
    const float* __restrict__ elr, const float* __restrict__ bias, float* __restrict__ h,
    unsigned short* __restrict__ hb, const unsigned short* __restrict__ wsz1,
    const float* __restrict__ al1, const float* __restrict__ ar1,
    unsigned short* __restrict__ feat_out, float* __restrict__ elr_out,
    const unsigned short* __restrict__ wlrsz, float* __restrict__ elr2_out) {
  __shared__ float a_lds[4][64];
  __shared__ float zi_lds[4][8];
  __shared__ __align__(16) unsigned short nh_lds[4][128];
  __shared__ int pnode[4];
  const int wid = threadIdx.x >> 6;
  const int t = perm[blockIdx.x * 4 + wid];
  const int lane = threadIdx.x & 63;
  const int e_loc = lane >> 3, hh = lane & 7;
  const int hg = lane >> 3;  // head for dims 2*lane, 2*lane+1
  const int beg = off[t], end = off[t + 1];
  const float ert = elr[t * 16 + 8 + hh];
  if (lane == 0) pnode[wid] = t;

  // 2-deep pipeline state
  int eA = beg + e_loc;
  bool vA = eA < end;
  int sA = vA ? csr_src[eA] : 0;
  float xA = vA ? elr[sA * 16 + hh] : 0.f;
  int eB = beg + 8 + e_loc;
  bool vB = eB < end;
  int sB = vB ? csr_src[eB] : 0;
  float xB = vB ? elr[sB * 16 + hh] : 0.f;

  unsigned int hvc[8];
  {
    int n0 = end - beg;
    if (n0 > 8) n0 = 8;
#pragma unroll
    for (int e2 = 0; e2 < 8; ++e2) {
      if (e2 < n0) {
        int s2 = __shfl(sA, e2 * 8, 64);
        hvc[e2] = *(const unsigned int*)&feat[(size_t)s2 * 128 + 2 * lane];
      }
    }
  }

  float z = 0.f, acc0 = 0.f, acc1 = 0.f;
  for (int base = beg; base < end; base += 8) {
    float ex = 0.f;
    if (vA) {
      float xv = xA + ert;
      xv = xv > 0.f ? xv : 0.2f * xv;
      ex = __expf(xv);
    }
    a_lds[wid][lane] = ex;
    __builtin_amdgcn_wave_barrier();
    asm volatile("s_waitcnt lgkmcnt(0)" ::: "memory");
    z += ex;

    // issue NEXT chunk's row gathers (overlap with this chunk's FMAs)
    unsigned int hvn[8];
    int n1 = end - base - 8;
    if (n1 > 8) n1 = 8;
#pragma unroll
    for (int e2 = 0; e2 < 8; ++e2) {
      if (e2 < n1) {
        int s2 = __shfl(sB, e2 * 8, 64);
        hvn[e2] = *(const unsigned int*)&feat[(size_t)s2 * 128 + 2 * lane];
      }
    }
    // prefetch chunk+2 edge info
    int eC = base + 16 + e_loc;
    bool vC = eC < end;
    int sC = vC ? csr_src[eC] : 0;
    float xC = vC ? elr[sC * 16 + hh] : 0.f;

    int n = end - base;
    if (n > 8) n = 8;
#pragma unroll
    for (int e2 = 0; e2 < 8; ++e2) {
      if (e2 < n) {
        float a = a_lds[wid][e2 * 8 + hg];
        acc0 += a * b2f((unsigned short)(hvc[e2] & 0xffffu));
        acc1 += a * b2f((unsigned short)(hvc[e2] >> 16));
      }
    }
    __builtin_amdgcn_wave_barrier();
#pragma unroll
    for (int e2 = 0; e2 < 8; ++e2) hvc[e2] = hvn[e2];
    sA = sB; xA = xB; vA = vB;
    sB = sC; xB = xC; vB = vC;
  }
  z += __shfl_xor(z, 8, 64);
  z += __shfl_xor(z, 16, 64);
  z += __shfl_xor(z, 32, 64);
  if (e_loc == 0) zi_lds[wid][hh] = (z > 0.f) ? 1.f / z : 0.f;
  __builtin_amdgcn_wave_barrier();
  asm volatile("s_waitcnt lgkmcnt(0)" ::: "memory");
  float zi = zi_lds[wid][hg];

  float2 bv = *(const float2*)&bias[2 * lane];
  float v0 = acc0 * zi + bv.x;
  float v1 = acc1 * zi + bv.y;
  v0 = v0 > 0.f ? v0 : expm1f(v0);
  v1 = v1 > 0.f ? v1 : expm1f(v1);
  size_t idx = (size_t)t * 128 + 2 * lane;
  float2 hv = *(const float2*)&h[idx];
  float nh0 = hv.x + v0;
  float nh1 = hv.y + v1;
  *(float2*)&h[idx] = make_float2(nh0, nh1);
  unsigned short b0 = f2b(nh0), b1 = f2b(nh1);
  *(ushort2*)&hb[idx] = make_ushort2(b0, b1);
  *(ushort2*)&nh_lds[wid][2 * lane] = make_ushort2(b0, b1);

  if (MODE == 1) {
    __builtin_amdgcn_wave_barrier();
    asm volatile("s_waitcnt lgkmcnt(0)" ::: "memory");
    const int kg = lane >> 4;
    f32x4 acc = {0.f, 0.f, 0.f, 0.f};
#pragma unroll
    for (int ks = 0; ks < 4; ++ks) {
      bf16x8 a = *(const bf16x8*)&nh_lds[wid][ks * 32 + kg * 8];
      bf16x8 b = *(const bf16x8*)(wlrsz + (((size_t)ks * 64 + lane) << 3));
      acc = __builtin_amdgcn_mfma_f32_16x16x32_bf16(a, b, acc, 0, 0, 0);
    }
    if (lane < 16) elr2_out[t * 16 + lane] = acc[0];
  }

  if (MODE == 0) {
    __syncthreads();
    const int r16 = lane & 15;
    const int kg = lane >> 4;
    f32x4 acc2[2];
    acc2[0] = {0.f, 0.f, 0.f, 0.f};
    acc2[1] = {0.f, 0.f, 0.f, 0.f};
#pragma unroll
    for (int ks = 0; ks < 4; ++ks) {
      bf16x8 a = {0, 0, 0, 0, 0, 0, 0, 0};
      if (r16 < 4) a = *(const bf16x8*)&nh_lds[r16][ks * 32 + kg * 8];
#pragma unroll
      for (int fi = 0; fi < 2; ++fi) {
        int f = wid * 2 + fi;
        bf16x8 b = *(const bf16x8*)(wsz1 + (((size_t)(ks * 8 + f) * 64 + lane) << 3));
        acc2[fi] = __builtin_amdgcn_mfma_f32_16x16x32_bf16(a, b, acc2[fi], 0, 0, 0);
      }
    }
    const int rowl = (lane >> 4) * 4;
#pragma unroll
    for (int fi = 0; fi < 2; ++fi) {
      int f = wid * 2 + fi;
      int col = f * 16 + r16;
      float alv = al1[col];
      float arv = ar1[col];
#pragma unroll
      for (int r = 0; r < 4; ++r) {
        float v = acc2[fi][r];
        if (rowl == 0) feat_out[(size_t)pnode[r] * 128 + col] = f2b(v);
        float pl = v * alv;
        float pr = v * arv;
#pragma unroll
        for (int msk = 1; msk < 16; msk <<= 1) {
          pl += __shfl_xor(pl, msk, 64);
          pr += __shfl_xor(pr, msk, 64);
        }
        if (r16 == 0 && rowl == 0) {
          int pn = pnode[r];
          elr_out[pn * 16 + f] = pl;
          elr_out[pn * 16 + 8 + f] = pr;
        }
      }
    }
  }
}

// ---------------- last layer: fused agg (1 node/wave, double-buffered gathers) + in-block GEMM ----------------
#define GT_STRIDE 1032
__global__ __launch_bounds__(1024) void agg_gemm16(
    const int* __restrict__ perm, const int* __restrict__ off,
    const int* __restrict__ csr_src, const unsigned short* __restrict__ hb,
    const float* __restrict__ elr, const unsigned short* __restrict__ wpsz,
    const float* __restrict__ hres, const float* __restrict__ mb,
    float* __restrict__ out) {
  __shared__ __align__(16) unsigned short gt[16][GT_STRIDE];
  __shared__ float red[8][64][4];
  __shared__ float a_lds[16][64];
  __shared__ float zi_lds[16][8];
  __shared__ int pnode[16];
  const int wid = threadIdx.x >> 6;
  const int lane = threadIdx.x & 63;
  const int t0 = blockIdx.x * 16;
  const int t = perm[t0 + wid];
  const int e_loc = lane >> 3, hh = lane & 7;
  if (lane == 0) pnode[wid] = t;

  // ---- phase 1: aggregate node t (1 node/wave, 2-chunk-deep gather pipeline) ----
  {
    const int beg = off[t], end = off[t + 1];
    const float ert = elr[t * 16 + 8 + hh];

    int eA = beg + e_loc;
    bool vA = eA < end;
    int sA = vA ? csr_src[eA] : 0;
    float xA = vA ? elr[sA * 16 + hh] : 0.f;
    int eB = beg + 8 + e_loc;
    bool vB = eB < end;
    int sB = vB ? csr_src[eB] : 0;
    float xB = vB ? elr[sB * 16 + hh] : 0.f;

    unsigned int hvc[8];
    {
      int n0 = end - beg;
      if (n0 > 8) n0 = 8;
#pragma unroll
      for (int e2 = 0; e2 < 8; ++e2) {
        if (e2 < n0) {
          int s2 = __shfl(sA, e2 * 8, 64);
          hvc[e2] = *(const unsigned int*)&hb[(size_t)s2 * 128 + 2 * lane];
        }
      }
    }

    float z = 0.f;
    float accA[8], accB[8];
#pragma unroll
    for (int k = 0; k < 8; ++k) accA[k] = accB[k] = 0.f;

    for (int base = beg; base < end; base += 8) {
      float ex = 0.f;
      if (vA) {
        float xv = xA + ert;
        xv = xv > 0.f ? xv : 0.2f * xv;
        ex = __expf(xv);
      }
      a_lds[wid][lane] = ex;
      __builtin_amdgcn_wave_barrier();
      asm volatile("s_waitcnt lgkmcnt(0)" ::: "memory");
      z += ex;

      unsigned int hvn[8];
      int n1 = end - base - 8;
      if (n1 > 8) n1 = 8;
#pragma unroll
      for (int e2 = 0; e2 < 8; ++e2) {
        if (e2 < n1) {
          int s2 = __shfl(sB, e2 * 8, 64);
          hvn[e2] = *(const unsigned int*)&hb[(size_t)s2 * 128 + 2 * lane];
        }
      }
      int eC = base + 16 + e_loc;
      bool vC = eC < end;
      int sC = vC ? csr_src[eC] : 0;
      float xC = vC ? elr[sC * 16 + hh] : 0.f;

      int n = end - base;
      if (n > 8) n = 8;
#pragma unroll
      for (int e2 = 0; e2 < 8; ++e2) {
        if (e2 < n) {
          float4 pa = *(const float4*)&a_lds[wid][e2 * 8];
          float4 pb = *(const float4*)&a_lds[wid][e2 * 8 + 4];
          float h0 = b2f((unsigned short)(hvc[e2] & 0xffffu));
          float h1 = b2f((unsigned short)(hvc[e2] >> 16));
          accA[0] += pa.x * h0; accB[0] += pa.x * h1;
          accA[1] += pa.y * h0; accB[1] += pa.y * h1;
          accA[2] += pa.z * h0; accB[2] += pa.z * h1;
          accA[3] += pa.w * h0; accB[3] += pa.w * h1;
          accA[4] += pb.x * h0; accB[4] += pb.x * h1;
          accA[5] += pb.y * h0; accB[5] += pb.y * h1;
          accA[6] += pb.z * h0; accB[6] += pb.z * h1;
          accA[7] += pb.w * h0; accB[7] += pb.w * h1;
        }
      }
      __builtin_amdgcn_wave_barrier();
#pragma unroll
      for (int e2 = 0; e2 < 8; ++e2) hvc[e2] = hvn[e2];
      sA = sB; xA = xB; vA = vB;
      sB = sC; xB = xC; vB = vC;
    }
    z += __shfl_xor(z, 8, 64);
    z += __shfl_xor(z, 16, 64);
    z += __shfl_xor(z, 32, 64);
    if (e_loc == 0) zi_lds[wid][hh] = (z > 0.f) ? 1.f / z : 0.f;
    __builtin_amdgcn_wave_barrier();
    asm volatile("s_waitcnt lgkmcnt(0)" ::: "memory");
    float4 zia = *(const float4*)&zi_lds[wid][0];
    float4 zib = *(const float4*)&zi_lds[wid][4];
    float ziv[8] = {zia.x, zia.y, zia.z, zia.w, zib.x, zib.y, zib.z, zib.w};
#pragma unroll
    for (int h2 = 0; h2 < 8; ++h2) {
      *(ushort2*)&gt[wid][h2 * 128 + 2 * lane] =
          make_ushort2(f2b(accA[h2] * ziv[h2]), f2b(accB[h2] * ziv[h2]));
    }
  }
  __syncthreads();

  // ---- phase 2: out[block's 16 nodes] = gt @ wpsz + hres + mb ----
  const int f = wid & 7;
  const int kh = wid >> 3;
  const int ar16 = lane & 15;
  const int kg = lane >> 4;
  f32x4 acc = {0.f, 0.f, 0.f, 0.f};
#pragma unroll 4
  for (int ksl = 0; ksl < 16; ++ksl) {
    int ks = kh * 16 + ksl;
    bf16x8 a = *(const bf16x8*)&gt[ar16][ks * 32 + kg * 8];
    bf16x8 b = *(const bf16x8*)(wpsz + (((size_t)(ks * 8 + f) * 64 + lane) << 3));
    acc = __builtin_amdgcn_mfma_f32_16x16x32_bf16(a, b, acc, 0, 0, 0);
  }
  if (kh == 1) {
    *(float4*)&red[f][lane][0] = make_float4(acc[0], acc[1], acc[2], acc[3]);
  }
  __syncthreads();
  if (kh == 0) {
    float4 p = *(const float4*)&red[f][lane][0];
    const int col = f * 16 + (lane & 15);
    const int rb = (lane >> 4) * 4;
    float r4[4] = {p.x, p.y, p.z, p.w};
#pragma unroll
    for (int r = 0; r < 4; ++r) {
      int row = pnode[rb + r];
      out[(size_t)row * 128 + col] =
          acc[r] + r4[r] + hres[(size_t)row * 128 + col] + mb[col];
    }
  }
}

extern "C" void kernel_launch(void* const* d_in, const int* in_sizes, int n_in,
                              void* d_out, int out_size, void* d_ws, size_t ws_size,
                              hipStream_t stream) {
  const float* x = (const float*)d_in[0];
  const int* src = (const int*)d_in[1];
  const int* dst = (const int*)d_in[2];
  const float* Ws = (const float*)d_in[3];
  const float* als = (const float*)d_in[4];
  const float* ars = (const float*)d_in[5];
  const float* bs = (const float*)d_in[6];
  const float* W_last = (const float*)d_in[7];
  const float* al_last = (const float*)d_in[8];
  const float* ar_last = (const float*)d_in[9];
  const float* b_last = (const float*)d_in[10];
  float* out = (float*)d_out;

  // ---- workspace layout ----
  float* h = (float*)d_ws;                           // 2,560,000 f
  float* elr0 = h + 2560000;                         // 320,000 f
  float* elrB = elr0 + 320000;                       // 320,000 f
  float* elr2 = elrB + 320000;                       // 320,000 f
  float* mb = elr2 + 320000;                         // 128 f
  unsigned short* hb = (unsigned short*)(mb + 128);  // 2,560,000 us
  unsigned short* featA = hb + 2560000;              // 2,560,000 us
  unsigned short* featB = featA + 2560000;           // 2,560,000 us
  unsigned short* wsz = featB + 2560000;             // 32,768 us
  unsigned short* wpsz = wsz + 32768;                // 131,072 us
  unsigned short* wlrsz = wpsz + 131072;             // 2,048 us
  int* deg = (int*)(wlrsz + 2048);                   // N
  int* off = deg + N_NODES;                          // N+1
  int* rank = off + N_NODES + 1;                     // E
  int* csr_src = rank + N_EDGES;                     // E
  int* perm = csr_src + N_EDGES;                     // N
  int* bbase_g = perm + N_NODES;                     // 64
  int* bcur_g = bbase_g + 64;                        // 64

  const int GB = N_NODES / 32;            // 625
  const int FB = N_NODES / 4;             // 5000
  const int EB = (N_EDGES + 255) / 256;   // 782
  const int PB = (N_NODES + 255) / 256;   // 79

  degzero<<<(N_NODES + 255) / 256, 256, 0, stream>>>(deg);
  prep_all<<<(N_NODES * DM / 4 + 255) / 256, 256, 0, stream>>>(
      x, h, hb, dst, deg, rank, Ws, wsz, W_last, wpsz, al_last, ar_last, b_last, wlrsz, mb);
  scan_deg<<<1, 1024, 0, stream>>>(deg, off, bbase_g, bcur_g);
  gemm0_scatter<<<GB + EB + PB, 256, 0, stream>>>(hb, wsz, featA, als, ars, elr0, src,
                                                  dst, rank, off, csr_src, deg, bbase_g,
                                                  bcur_g, perm);
  fused_small<0><<<FB, 256, 0, stream>>>(perm, off, csr_src, featA, elr0, bs, h, hb,
                                         wsz + 16384, als + 128, ars + 128, featB, elrB,
                                         nullptr, nullptr);
  fused_small<1><<<FB, 256, 0, stream>>>(perm, off, csr_src, featB, elrB, bs + 128, h, hb,
                                         nullptr, nullptr, nullptr, nullptr, nullptr,
                                         wlrsz, elr2);
  agg_gemm16<<<N_NODES / 16, 1024, 0, stream>>>(perm, off, csr_src, hb, elr2, wpsz, h, mb,
                                                out);
}

// Round 26
// 158.131 us; speedup vs baseline: 1.0901x; 1.0901x over previous
//
#include <hip/hip_runtime.h>
#include <math.h>

#define N_NODES 20000
#define N_EDGES 200000
#define DM 128
#define NH 8

typedef __attribute__((ext_vector_type(8))) short bf16x8;
typedef __attribute__((ext_vector_type(4))) float f32x4;

__device__ __forceinline__ unsigned short f2b(float f) {
  unsigned int u = __float_as_uint(f);
  unsigned int r = (u + 0x7FFFu + ((u >> 16) & 1u)) >> 16;  // RNE
  return (unsigned short)r;
}
__device__ __forceinline__ float b2f(unsigned short s) {
  return __uint_as_float(((unsigned int)s) << 16);
}

// ---------------- deg zero ----------------
__global__ __launch_bounds__(256) void degzero(int* __restrict__ deg) {
  int i = blockIdx.x * 256 + threadIdx.x;
  if (i < N_NODES) deg[i] = 0;
}

// ---------------- prep: cast + edge count(rank) + all weight prep ----------------
__global__ __launch_bounds__(256) void prep_all(
    const float* __restrict__ x, float* __restrict__ h, unsigned short* __restrict__ hb,
    const int* __restrict__ dstE, int* __restrict__ deg, int* __restrict__ rank,
    const float* __restrict__ Ws, unsigned short* __restrict__ wsz,
    const float* __restrict__ W_last, unsigned short* __restrict__ wpsz,
    const float* __restrict__ al_last, const float* __restrict__ ar_last,
    const float* __restrict__ b_last, unsigned short* __restrict__ wlrsz,
    float* __restrict__ mb) {
  int i = blockIdx.x * 256 + threadIdx.x;
  if (i < (N_NODES * DM) / 4) {  // float4 cast
    float4 v = ((const float4*)x)[i];
    ((float4*)h)[i] = v;
    ((ushort4*)hb)[i] = make_ushort4(f2b(v.x), f2b(v.y), f2b(v.z), f2b(v.w));
  }
  if (i < N_EDGES) rank[i] = atomicAdd(&deg[dstE[i]], 1);
  if (i < 2 * 16384) {  // layers 0/1 B swizzle
    int layer = i >> 14;
    int r = i & 16383;
    int j = r & 7, l = (r >> 3) & 63, f = (r >> 9) & 7, ks = r >> 12;
    int k = ks * 32 + ((l >> 4) << 3) + j;
    int n = f * 16 + (l & 15);
    wsz[i] = f2b(Ws[(size_t)layer * 16384 + k * 128 + n]);
  }
  if (i < 131072) {  // last-layer B swizzle (1/8 mean folded)
    int j = i & 7, l = (i >> 3) & 63, f = (i >> 9) & 7, ks = i >> 12;
    int k = ks * 32 + ((l >> 4) << 3) + j;
    int n = f * 16 + (l & 15);
    int h_ = k >> 7, ko = k & 127;
    wpsz[i] = f2b(W_last[(size_t)ko * 1024 + h_ * 128 + n] * 0.125f);
  }
  if (i < 2048) {  // wlr fragment build
    int j = i & 7, l = (i >> 3) & 63, ks = i >> 9;
    int k = ks * 32 + ((l >> 4) << 3) + j;
    int n = l & 15;
    int hh = n & 7;
    const float* av = (n < 8) ? (al_last + hh * 128) : (ar_last + hh * 128);
    float s = 0.f;
    for (int d = 0; d < 128; ++d) s += W_last[(size_t)k * 1024 + hh * 128 + d] * av[d];
    wlrsz[i] = f2b(s);
  }
  if (i < 128) {
    float s = 0.f;
#pragma unroll
    for (int hh = 0; hh < 8; ++hh) s += b_last[hh * 128 + i];
    mb[i] = s * 0.125f;
  }
}

// ---------------- single-block (1024 thr): exclusive scan (off) + bucket bases ----------------
__global__ void scan_deg(const int* __restrict__ deg, int* __restrict__ off,
                         int* __restrict__ bbase_g, int* __restrict__ bcur_g) {
  __shared__ int part[1024];
  __shared__ int hist[16][64];
  const int tid = threadIdx.x;
  const int wv = tid >> 6, lane = tid & 63;
  const int CHUNK = (N_NODES + 1023) / 1024;  // 20
  int base = tid * CHUNK;

  for (int i = tid; i < 16 * 64; i += 1024) ((int*)hist)[i] = 0;
  __syncthreads();

  int s = 0;
  for (int i = 0; i < CHUNK; ++i) {
    int idx = base + i;
    if (idx < N_NODES) {
      int d = deg[idx];
      s += d;
      atomicAdd(&hist[wv][min(d, 63)], 1);
    }
  }
  part[tid] = s;
  __syncthreads();
  for (int ofs = 1; ofs < 1024; ofs <<= 1) {
    int v = (tid >= ofs) ? part[tid - ofs] : 0;
    __syncthreads();
    part[tid] += v;
    __syncthreads();
  }
  int run = (tid > 0) ? part[tid - 1] : 0;
  for (int i = 0; i < CHUNK; ++i) {
    int idx = base + i;
    if (idx < N_NODES) {
      off[idx] = run;
      run += deg[idx];
    }
  }
  if (tid == 0) off[N_NODES] = part[1023];

  // bucket bases: wave 0 reduces the 16 sub-histograms + shfl exclusive scan
  if (wv == 0) {
    int c = 0;
#pragma unroll
    for (int w = 0; w < 16; ++w) c += hist[w][lane];
    int inc = c;
#pragma unroll
    for (int ofs = 1; ofs < 64; ofs <<= 1) {
      int v = __shfl_up(inc, ofs, 64);
      if (lane >= ofs) inc += v;
    }
    bbase_g[lane] = inc - c;  // exclusive
    bcur_g[lane] = 0;
  }
}

// ---------------- MFMA GEMM device body (layer 0) ----------------
template <int K>
__device__ __forceinline__ void dev_gemm(int tile, const unsigned short* __restrict__ A,
                                         const unsigned short* __restrict__ Bsz,
                                         unsigned short* __restrict__ Cb,
                                         const float* __restrict__ al,
                                         const float* __restrict__ ar,
                                         float* __restrict__ elr, int lane, int wid) {
  const int wrow = wid & 1, wc = wid >> 1;
  const int r0 = tile * 32;
  const int arow = r0 + wrow * 16 + (lane & 15);
  const int kg = lane >> 4;

  f32x4 acc[4];
#pragma unroll
  for (int fi = 0; fi < 4; ++fi) acc[fi] = {0.f, 0.f, 0.f, 0.f};

  const bf16x8* Ap = (const bf16x8*)(A + (size_t)arow * K + kg * 8);
#pragma unroll 4
  for (int ks = 0; ks < K / 32; ++ks) {
    bf16x8 a = Ap[ks * 4];
#pragma unroll
    for (int fi = 0; fi < 4; ++fi) {
      int f = wc * 4 + fi;
      bf16x8 b = *(const bf16x8*)(Bsz + (((size_t)(ks * 8 + f) * 64 + lane) << 3));
      acc[fi] = __builtin_amdgcn_mfma_f32_16x16x32_bf16(a, b, acc[fi], 0, 0, 0);
    }
  }

  const int rbase = r0 + wrow * 16 + (lane >> 4) * 4;
#pragma unroll
  for (int fi = 0; fi < 4; ++fi) {
    int col = wc * 64 + fi * 16 + (lane & 15);
#pragma unroll
    for (int r = 0; r < 4; ++r) {
      Cb[(size_t)(rbase + r) * DM + col] = f2b(acc[fi][r]);
    }
  }

  // fused attn scores
#pragma unroll
  for (int fi = 0; fi < 4; ++fi) {
    int hh = wc * 4 + fi;
    float alv = al[hh * 16 + (lane & 15)];
    float arv = ar[hh * 16 + (lane & 15)];
#pragma unroll
    for (int r = 0; r < 4; ++r) {
      float pl = acc[fi][r] * alv;
      float pr = acc[fi][r] * arv;
#pragma unroll
      for (int msk = 1; msk < 16; msk <<= 1) {
        pl += __shfl_xor(pl, msk, 64);
        pr += __shfl_xor(pr, msk, 64);
      }
      if ((lane & 15) == 0) {
        int row = rbase + r;
        elr[row * 16 + hh] = pl;
        elr[row * 16 + 8 + hh] = pr;
      }
    }
  }
}

// layer0 GEMM || rank-based CSR scatter || perm scatter (block-aggregated atomics)
__global__ __launch_bounds__(256) void gemm0_scatter(
    const unsigned short* __restrict__ A, const unsigned short* __restrict__ Bsz,
    unsigned short* __restrict__ Cb, const float* __restrict__ al,
    const float* __restrict__ ar, float* __restrict__ elr, const int* __restrict__ srcE,
    const int* __restrict__ dstE, const int* __restrict__ rank,
    const int* __restrict__ off, int* __restrict__ csr_src, const int* __restrict__ deg,
    const int* __restrict__ bbase_g, int* __restrict__ bcur_g, int* __restrict__ perm) {
  __shared__ int lcnt[64];
  __shared__ int gbase[64];
  const int bid = blockIdx.x;
  const int GB = N_NODES / 32;
  const int EB = (N_EDGES + 255) / 256;
  if (bid < GB) {
    dev_gemm<DM>(bid, A, Bsz, Cb, al, ar, elr, threadIdx.x & 63, threadIdx.x >> 6);
  } else if (bid < GB + EB) {
    int e = (bid - GB) * 256 + threadIdx.x;
    if (e < N_EDGES) {
      csr_src[off[dstE[e]] + rank[e]] = srcE[e];
    }
  } else {
    // perm scatter: LDS-local ranks + ONE global atomic per (block, nonzero bucket)
    const int tid = threadIdx.x;
    int idx = (bid - GB - EB) * 256 + tid;
    if (tid < 64) lcnt[tid] = 0;
    __syncthreads();
    int d = 0, lrank = 0;
    bool valid = idx < N_NODES;
    if (valid) {
      d = min(deg[idx], 63);
      lrank = atomicAdd(&lcnt[d], 1);  // <=4-way LDS contention, cheap
    }
    __syncthreads();
    if (tid < 64 && lcnt[tid] > 0) gbase[tid] = atomicAdd(&bcur_g[tid], lcnt[tid]);
    __syncthreads();
    if (valid) perm[bbase_g[d] + gbase[d] + lrank] = idx;
  }
}

// ---------------- layers 0/1: fused softmax+agg (perm-balanced) ----------------
template <int MODE>
__global__ __launch_bounds__(256) void fused_small(
    const int* __restrict__ perm, const int* __restrict__ off,
    const int* __restrict__ csr_src, const unsigned short* __restrict__ feat,
    const float* __restrict__ elr, const float* __restrict__ bias, float* __restrict__ h,
    unsigned short* __restrict__ hb, const unsigned short* __restrict__ wsz1,
    const float* __restrict__ al1, const float* __restrict__ ar1,
    unsigned short* __restrict__ feat_out, float* __restrict__ elr_out,
    const unsigned short* __restrict__ wlrsz, float* __restrict__ elr2_out) {
  __shared__ float a_lds[4][64];
  __shared__ int s_lds[4][8];
  __shared__ float zi_lds[4][8];
  __shared__ __align__(16) unsigned short nh_lds[4][128];
  __shared__ int pnode[4];
  const int wid = threadIdx.x >> 6;
  const int t = perm[blockIdx.x * 4 + wid];
  const int lane = threadIdx.x & 63;
  const int e_loc = lane >> 3, hh = lane & 7;
  const int hg = lane >> 3;
  const int beg = off[t], end = off[t + 1];
  const float ert = elr[t * 16 + 8 + hh];
  if (lane == 0) pnode[wid] = t;

  int e = beg + e_loc;
  bool val = e < end;
  int s = val ? csr_src[e] : 0;
  float xl = val ? elr[s * 16 + hh] : 0.f;

  float z = 0.f, acc0 = 0.f, acc1 = 0.f;
  for (int base = beg; base < end; base += 8) {
    float ex = 0.f;
    if (val) {
      float xv = xl + ert;
      xv = xv > 0.f ? xv : 0.2f * xv;
      ex = __expf(xv);
    }
    a_lds[wid][lane] = ex;
    if (hh == 0) s_lds[wid][e_loc] = s;
    __builtin_amdgcn_wave_barrier();
    asm volatile("s_waitcnt lgkmcnt(0)" ::: "memory");
    z += ex;
    int en = base + 8 + e_loc;
    bool valn = en < end;
    int sn = valn ? csr_src[en] : 0;
    float xln = valn ? elr[sn * 16 + hh] : 0.f;
    int n = min(8, end - base);
    if (n == 8) {
#pragma unroll
      for (int e2 = 0; e2 < 8; ++e2) {
        int s2 = s_lds[wid][e2];
        float a = a_lds[wid][e2 * 8 + hg];
        unsigned int hv = *(const unsigned int*)&feat[(size_t)s2 * 128 + 2 * lane];
        acc0 += a * b2f((unsigned short)(hv & 0xffffu));
        acc1 += a * b2f((unsigned short)(hv >> 16));
      }
    } else {
      for (int e2 = 0; e2 < n; ++e2) {
        int s2 = s_lds[wid][e2];
        float a = a_lds[wid][e2 * 8 + hg];
        unsigned int hv = *(const unsigned int*)&feat[(size_t)s2 * 128 + 2 * lane];
        acc0 += a * b2f((unsigned short)(hv & 0xffffu));
        acc1 += a * b2f((unsigned short)(hv >> 16));
      }
    }
    __builtin_amdgcn_wave_barrier();
    s = sn;
    xl = xln;
    val = valn;
  }
  z += __shfl_xor(z, 8, 64);
  z += __shfl_xor(z, 16, 64);
  z += __shfl_xor(z, 32, 64);
  if (e_loc == 0) zi_lds[wid][hh] = (z > 0.f) ? 1.f / z : 0.f;
  __builtin_amdgcn_wave_barrier();
  asm volatile("s_waitcnt lgkmcnt(0)" ::: "memory");
  float zi = zi_lds[wid][hg];

  float2 bv = *(const float2*)&bias[2 * lane];
  float v0 = acc0 * zi + bv.x;
  float v1 = acc1 * zi + bv.y;
  v0 = v0 > 0.f ? v0 : expm1f(v0);
  v1 = v1 > 0.f ? v1 : expm1f(v1);
  size_t idx = (size_t)t * 128 + 2 * lane;
  float2 hv = *(const float2*)&h[idx];
  float nh0 = hv.x + v0;
  float nh1 = hv.y + v1;
  *(float2*)&h[idx] = make_float2(nh0, nh1);
  unsigned short b0 = f2b(nh0), b1 = f2b(nh1);
  *(ushort2*)&hb[idx] = make_ushort2(b0, b1);
  *(ushort2*)&nh_lds[wid][2 * lane] = make_ushort2(b0, b1);

  if (MODE == 1) {
    __builtin_amdgcn_wave_barrier();
    asm volatile("s_waitcnt lgkmcnt(0)" ::: "memory");
    const int kg = lane >> 4;
    f32x4 acc = {0.f, 0.f, 0.f, 0.f};
#pragma unroll
    for (int ks = 0; ks < 4; ++ks) {
      bf16x8 a = *(const bf16x8*)&nh_lds[wid][ks * 32 + kg * 8];
      bf16x8 b = *(const bf16x8*)(wlrsz + (((size_t)ks * 64 + lane) << 3));
      acc = __builtin_amdgcn_mfma_f32_16x16x32_bf16(a, b, acc, 0, 0, 0);
    }
    if (lane < 16) elr2_out[t * 16 + lane] = acc[0];
  }

  if (MODE == 0) {
    __syncthreads();
    const int r16 = lane & 15;
    const int kg = lane >> 4;
    f32x4 acc2[2];
    acc2[0] = {0.f, 0.f, 0.f, 0.f};
    acc2[1] = {0.f, 0.f, 0.f, 0.f};
#pragma unroll
    for (int ks = 0; ks < 4; ++ks) {
      bf16x8 a = {0, 0, 0, 0, 0, 0, 0, 0};
      if (r16 < 4) a = *(const bf16x8*)&nh_lds[r16][ks * 32 + kg * 8];
#pragma unroll
      for (int fi = 0; fi < 2; ++fi) {
        int f = wid * 2 + fi;
        bf16x8 b = *(const bf16x8*)(wsz1 + (((size_t)(ks * 8 + f) * 64 + lane) << 3));
        acc2[fi] = __builtin_amdgcn_mfma_f32_16x16x32_bf16(a, b, acc2[fi], 0, 0, 0);
      }
    }
    const int rowl = (lane >> 4) * 4;
#pragma unroll
    for (int fi = 0; fi < 2; ++fi) {
      int f = wid * 2 + fi;
      int col = f * 16 + r16;
      float alv = al1[col];
      float arv = ar1[col];
#pragma unroll
      for (int r = 0; r < 4; ++r) {
        float v = acc2[fi][r];
        if (rowl == 0) feat_out[(size_t)pnode[r] * 128 + col] = f2b(v);
        float pl = v * alv;
        float pr = v * arv;
#pragma unroll
        for (int msk = 1; msk < 16; msk <<= 1) {
          pl += __shfl_xor(pl, msk, 64);
          pr += __shfl_xor(pr, msk, 64);
        }
        if (r16 == 0 && rowl == 0) {
          int pn = pnode[r];
          elr_out[pn * 16 + f] = pl;
          elr_out[pn * 16 + 8 + f] = pr;
        }
      }
    }
  }
}

// ---------------- last layer: fused agg (1 node/wave, double-buffered gathers) + in-block GEMM ----------------
#define GT_STRIDE 1032
__global__ __launch_bounds__(1024) void agg_gemm16(
    const int* __restrict__ perm, const int* __restrict__ off,
    const int* __restrict__ csr_src, const unsigned short* __restrict__ hb,
    const float* __restrict__ elr, const unsigned short* __restrict__ wpsz,
    const float* __restrict__ hres, const float* __restrict__ mb,
    float* __restrict__ out) {
  __shared__ __align__(16) unsigned short gt[16][GT_STRIDE];
  __shared__ float red[8][64][4];
  __shared__ float a_lds[16][64];
  __shared__ float zi_lds[16][8];
  __shared__ int pnode[16];
  const int wid = threadIdx.x >> 6;
  const int lane = threadIdx.x & 63;
  const int t0 = blockIdx.x * 16;
  const int t = perm[t0 + wid];
  const int e_loc = lane >> 3, hh = lane & 7;
  if (lane == 0) pnode[wid] = t;

  // ---- phase 1: aggregate node t (1 node/wave, 2-chunk-deep gather pipeline) ----
  {
    const int beg = off[t], end = off[t + 1];
    const float ert = elr[t * 16 + 8 + hh];

    int eA = beg + e_loc;
    bool vA = eA < end;
    int sA = vA ? csr_src[eA] : 0;
    float xA = vA ? elr[sA * 16 + hh] : 0.f;
    int eB = beg + 8 + e_loc;
    bool vB = eB < end;
    int sB = vB ? csr_src[eB] : 0;
    float xB = vB ? elr[sB * 16 + hh] : 0.f;

    unsigned int hvc[8];
    {
      int n0 = end - beg;
      if (n0 > 8) n0 = 8;
#pragma unroll
      for (int e2 = 0; e2 < 8; ++e2) {
        if (e2 < n0) {
          int s2 = __shfl(sA, e2 * 8, 64);
          hvc[e2] = *(const unsigned int*)&hb[(size_t)s2 * 128 + 2 * lane];
        }
      }
    }

    float z = 0.f;
    float accA[8], accB[8];
#pragma unroll
    for (int k = 0; k < 8; ++k) accA[k] = accB[k] = 0.f;

    for (int base = beg; base < end; base += 8) {
      float ex = 0.f;
      if (vA) {
        float xv = xA + ert;
        xv = xv > 0.f ? xv : 0.2f * xv;
        ex = __expf(xv);
      }
      a_lds[wid][lane] = ex;
      __builtin_amdgcn_wave_barrier();
      asm volatile("s_waitcnt lgkmcnt(0)" ::: "memory");
      z += ex;

      unsigned int hvn[8];
      int n1 = end - base - 8;
      if (n1 > 8) n1 = 8;
#pragma unroll
      for (int e2 = 0; e2 < 8; ++e2) {
        if (e2 < n1) {
          int s2 = __shfl(sB, e2 * 8, 64);
          hvn[e2] = *(const unsigned int*)&hb[(size_t)s2 * 128 + 2 * lane];
        }
      }
      int eC = base + 16 + e_loc;
      bool vC = eC < end;
      int sC = vC ? csr_src[eC] : 0;
      float xC = vC ? elr[sC * 16 + hh] : 0.f;

      int n = end - base;
      if (n > 8) n = 8;
#pragma unroll
      for (int e2 = 0; e2 < 8; ++e2) {
        if (e2 < n) {
          float4 pa = *(const float4*)&a_lds[wid][e2 * 8];
          float4 pb = *(const float4*)&a_lds[wid][e2 * 8 + 4];
          float h0 = b2f((unsigned short)(hvc[e2] & 0xffffu));
          float h1 = b2f((unsigned short)(hvc[e2] >> 16));
          accA[0] += pa.x * h0; accB[0] += pa.x * h1;
          accA[1] += pa.y * h0; accB[1] += pa.y * h1;
          accA[2] += pa.z * h0; accB[2] += pa.z * h1;
          accA[3] += pa.w * h0; accB[3] += pa.w * h1;
          accA[4] += pb.x * h0; accB[4] += pb.x * h1;
          accA[5] += pb.y * h0; accB[5] += pb.y * h1;
          accA[6] += pb.z * h0; accB[6] += pb.z * h1;
          accA[7] += pb.w * h0; accB[7] += pb.w * h1;
        }
      }
      __builtin_amdgcn_wave_barrier();
#pragma unroll
      for (int e2 = 0; e2 < 8; ++e2) hvc[e2] = hvn[e2];
      sA = sB; xA = xB; vA = vB;
      sB = sC; xB = xC; vB = vC;
    }
    z += __shfl_xor(z, 8, 64);
    z += __shfl_xor(z, 16, 64);
    z += __shfl_xor(z, 32, 64);
    if (e_loc == 0) zi_lds[wid][hh] = (z > 0.f) ? 1.f / z : 0.f;
    __builtin_amdgcn_wave_barrier();
    asm volatile("s_waitcnt lgkmcnt(0)" ::: "memory");
    float4 zia = *(const float4*)&zi_lds[wid][0];
    float4 zib = *(const float4*)&zi_lds[wid][4];
    float ziv[8] = {zia.x, zia.y, zia.z, zia.w, zib.x, zib.y, zib.z, zib.w};
#pragma unroll
    for (int h2 = 0; h2 < 8; ++h2) {
      *(ushort2*)&gt[wid][h2 * 128 + 2 * lane] =
          make_ushort2(f2b(accA[h2] * ziv[h2]), f2b(accB[h2] * ziv[h2]));
    }
  }
  __syncthreads();

  // ---- phase 2: out[block's 16 nodes] = gt @ wpsz + hres + mb ----
  const int f = wid & 7;
  const int kh = wid >> 3;
  const int ar16 = lane & 15;
  const int kg = lane >> 4;
  f32x4 acc = {0.f, 0.f, 0.f, 0.f};
#pragma unroll 4
  for (int ksl = 0; ksl < 16; ++ksl) {
    int ks = kh * 16 + ksl;
    bf16x8 a = *(const bf16x8*)&gt[ar16][ks * 32 + kg * 8];
    bf16x8 b = *(const bf16x8*)(wpsz + (((size_t)(ks * 8 + f) * 64 + lane) << 3));
    acc = __builtin_amdgcn_mfma_f32_16x16x32_bf16(a, b, acc, 0, 0, 0);
  }
  if (kh == 1) {
    *(float4*)&red[f][lane][0] = make_float4(acc[0], acc[1], acc[2], acc[3]);
  }
  __syncthreads();
  if (kh == 0) {
    float4 p = *(const float4*)&red[f][lane][0];
    const int col = f * 16 + (lane & 15);
    const int rb = (lane >> 4) * 4;
    float r4[4] = {p.x, p.y, p.z, p.w};
#pragma unroll
    for (int r = 0; r < 4; ++r) {
      int row = pnode[rb + r];
      out[(size_t)row * 128 + col] =
          acc[r] + r4[r] + hres[(size_t)row * 128 + col] + mb[col];
    }
  }
}

extern "C" void kernel_launch(void* const* d_in, const int* in_sizes, int n_in,
                              void* d_out, int out_size, void* d_ws, size_t ws_size,
                              hipStream_t stream) {
  const float* x = (const float*)d_in[0];
  const int* src = (const int*)d_in[1];
  const int* dst = (const int*)d_in[2];
  const float* Ws = (const float*)d_in[3];
  const float* als = (const float*)d_in[4];
  const float* ars = (const float*)d_in[5];
  const float* bs = (const float*)d_in[6];
  const float* W_last = (const float*)d_in[7];
  const float* al_last = (const float*)d_in[8];
  const float* ar_last = (const float*)d_in[9];
  const float* b_last = (const float*)d_in[10];
  float* out = (float*)d_out;

  // ---- workspace layout ----
  float* h = (float*)d_ws;                           // 2,560,000 f
  float* elr0 = h + 2560000;                         // 320,000 f
  float* elrB = elr0 + 320000;                       // 320,000 f
  float* elr2 = elrB + 320000;                       // 320,000 f
  float* mb = elr2 + 320000;                         // 128 f
  unsigned short* hb = (unsigned short*)(mb + 128);  // 2,560,000 us
  unsigned short* featA = hb + 2560000;              // 2,560,000 us
  unsigned short* featB = featA + 2560000;           // 2,560,000 us
  unsigned short* wsz = featB + 2560000;             // 32,768 us
  unsigned short* wpsz = wsz + 32768;                // 131,072 us
  unsigned short* wlrsz = wpsz + 131072;             // 2,048 us
  int* deg = (int*)(wlrsz + 2048);                   // N
  int* off = deg + N_NODES;                          // N+1
  int* rank = off + N_NODES + 1;                     // E
  int* csr_src = rank + N_EDGES;                     // E
  int* perm = csr_src + N_EDGES;                     // N
  int* bbase_g = perm + N_NODES;                     // 64
  int* bcur_g = bbase_g + 64;                        // 64

  const int GB = N_NODES / 32;            // 625
  const int FB = N_NODES / 4;             // 5000
  const int EB = (N_EDGES + 255) / 256;   // 782
  const int PB = (N_NODES + 255) / 256;   // 79

  degzero<<<(N_NODES + 255) / 256, 256, 0, stream>>>(deg);
  prep_all<<<(N_NODES * DM / 4 + 255) / 256, 256, 0, stream>>>(
      x, h, hb, dst, deg, rank, Ws, wsz, W_last, wpsz, al_last, ar_last, b_last, wlrsz, mb);
  scan_deg<<<1, 1024, 0, stream>>>(deg, off, bbase_g, bcur_g);
  gemm0_scatter<<<GB + EB + PB, 256, 0, stream>>>(hb, wsz, featA, als, ars, elr0, src,
                                                  dst, rank, off, csr_src, deg, bbase_g,
                                                  bcur_g, perm);
  fused_small<0><<<FB, 256, 0, stream>>>(perm, off, csr_src, featA, elr0, bs, h, hb,
                                         wsz + 16384, als + 128, ars + 128, featB, elrB,
                                         nullptr, nullptr);
  fused_small<1><<<FB, 256, 0, stream>>>(perm, off, csr_src, featB, elrB, bs + 128, h, hb,
                                         nullptr, nullptr, nullptr, nullptr, nullptr,
                                         wlrsz, elr2);
  agg_gemm16<<<N_NODES / 16, 1024, 0, stream>>>(perm, off, csr_src, hb, elr2, wpsz, h, mb,
                                                out);
}